// Round 5
// baseline (519.623 us; speedup 1.0000x reference)
//
#include <hip/hip_runtime.h>
#include <hip/hip_bf16.h>

// Linear: C[M,N] = A[M,K] @ W[N,K]^T + bias[N]. fp32 in/out (harness maps fp16
// reference -> fp32 buffers), bf16 MFMA compute (2% threshold).
//
// Round 5: bigger tiles to cut LDS-read + staging bytes per FLOP (round-4 was
// LDS/staging bound: 63%/48% of cycles vs 13% MFMA floor).
//  - Block tile 256x128 (BMxBN), 4 waves as 2x2, wave tile 128x64.
//  - mfma_f32_32x32x16_bf16, acc[4][2] of f32x16 (~128 acc VGPRs).
//    A-op layout: m=lane&31, k=(lane>>5)*8+j. C/D: col=lane&31,
//    row=(reg&3)+8*(reg>>2)+4*(lane>>5)  [m74/m101-verified].
//  - Phase 1 pack: fp32->bf16, tile-blocked + XOR chunk swizzle
//    (cp = chunk ^ (row&7)); linear coalesced READS, swizzle on write side,
//    2 chunks (64B read / 32B write) per thread for ILP.
//  - Phase 2 gemm: global_load_lds width=16 (linear), swizzled ds_read_b128
//    (8-phase floor), nontemporal C stores (don't thrash L3's copy of A/W).

typedef unsigned short u16;
typedef unsigned int u32;
typedef __bf16 bf16x8 __attribute__((ext_vector_type(8)));
typedef float f32x4 __attribute__((ext_vector_type(4)));
typedef float f32x16 __attribute__((ext_vector_type(16)));
typedef u32 u32x4 __attribute__((ext_vector_type(4)));

#define M_DIM 8192
#define N_DIM 4096
#define K_DIM 4096
#define BM 256
#define BN 128
#define BK 64

#define KT (K_DIM / BK)                 // 64 k-tiles
#define AT_ELEMS (BM * BK)              // 16384 elems / A tile
#define WT_ELEMS (BN * BK)              // 8192 elems / W tile
#define AT_CH (AT_ELEMS / 8)            // 2048 chunks (16B) / A tile
#define WT_CH (WT_ELEMS / 8)            // 1024
#define A_CHUNKS ((M_DIM / BM) * KT * AT_CH)   // 4,194,304
#define W_CHUNKS ((N_DIM / BN) * KT * WT_CH)   // 2,097,152
#define A_PACK_BYTES ((size_t)A_CHUNKS * 16)   // 64 MiB
#define W_PACK_BYTES ((size_t)W_CHUNKS * 16)   // 32 MiB

// pack two fp32 -> (bf16(hi)<<16)|bf16(lo) by byte-perm truncation
__device__ __forceinline__ u32 pack2bf(float lo, float hi) {
    return __builtin_amdgcn_perm(__float_as_uint(hi), __float_as_uint(lo),
                                 0x07060302u);
}

__device__ __forceinline__ void g2l16(const u16* g, __bf16* l) {
    __builtin_amdgcn_global_load_lds((__attribute__((address_space(1))) void*)g,
                                     (__attribute__((address_space(3))) void*)l,
                                     16, 0, 0);
}

// ---------------- Phase 1: convert + tile-pack + swizzle ----------------
// Thread handles 2 consecutive SOURCE chunks (64B contiguous read, coalesced);
// writes land at cp = sc ^ (row&7) (adjacent pair: cp1 = cp0^1).
__global__ __launch_bounds__(256) void pack_bf16_kernel(
    const float* __restrict__ A, const float* __restrict__ W,
    u32x4* __restrict__ aP, u32x4* __restrict__ wP)
{
    const long t = (long)blockIdx.x * 256 + threadIdx.x;
    const long cid = t * 2;

    const float* src;
    u32x4* dst;
    long id, tbase;
    int row, sc, rows_l2;   // rows_l2: log2 chunks-per-tile
    if (cid < (long)A_CHUNKS) {
        id = cid;  src = A;  dst = aP;
        const int tile = (int)(id >> 11);          // 2048 chunks/tile
        const int slot = (int)(id & 2047);
        row = slot >> 3;                           // 0..255
        sc  = slot & 7;                            // even
        const int mt = tile >> 6, kt = tile & 63;
        src += (size_t)(mt * BM + row) * K_DIM + kt * BK + sc * 8;
        tbase = ((long)tile << 11) + row * 8;
    } else {
        id = cid - A_CHUNKS;  src = W;  dst = wP;
        const int tile = (int)(id >> 10);          // 1024 chunks/tile
        const int slot = (int)(id & 1023);
        row = slot >> 3;                           // 0..127
        sc  = slot & 7;
        const int nt = tile >> 6, kt = tile & 63;
        src += (size_t)(nt * BN + row) * K_DIM + kt * BK + sc * 8;
        tbase = ((long)tile << 10) + row * 8;
    }

    f32x4 v0 = *(const f32x4*)(src);
    f32x4 v1 = *(const f32x4*)(src + 4);
    f32x4 v2 = *(const f32x4*)(src + 8);
    f32x4 v3 = *(const f32x4*)(src + 12);

    const int cp0 = sc ^ (row & 7);
    dst[tbase + cp0] = u32x4{pack2bf(v0[0], v0[1]), pack2bf(v0[2], v0[3]),
                             pack2bf(v1[0], v1[1]), pack2bf(v1[2], v1[3])};
    dst[tbase + (cp0 ^ 1)] = u32x4{pack2bf(v2[0], v2[1]), pack2bf(v2[2], v2[3]),
                                   pack2bf(v3[0], v3[1]), pack2bf(v3[2], v3[3])};
}

// ---------------- Phase 2: GEMM from packed bf16 ----------------
__global__ __launch_bounds__(256, 2) void gemm_packed_kernel(
    const u16* __restrict__ aP,      // packed A tiles (256x64, swizzled)
    const u16* __restrict__ wP,      // packed W tiles (128x64, swizzled)
    const float* __restrict__ bias,  // [N] fp32
    float* __restrict__ C)           // [M, N] fp32
{
    __shared__ __attribute__((aligned(16))) __bf16 sA[AT_ELEMS];  // 32 KiB
    __shared__ __attribute__((aligned(16))) __bf16 sB[WT_ELEMS];  // 16 KiB

    const int tid  = threadIdx.x;
    const int lane = tid & 63;
    const int wave = tid >> 6;
    const int half = lane >> 5;       // 0..1
    const int l32  = lane & 31;
    const int wm   = wave >> 1;       // wave row (2x2 wave grid)
    const int wn   = wave & 1;        // wave col

    const int bn = blockIdx.x;        // 32 N-tiles
    const int bm = blockIdx.y;        // 32 M-tiles

    const u16* aT = aP + (size_t)bm * KT * AT_ELEMS + tid * 8;
    const u16* wT = wP + (size_t)bn * KT * WT_ELEMS + tid * 8;
    __bf16* sAp = &sA[tid * 8];
    __bf16* sBp = &sB[tid * 8];

    f32x16 acc[4][2];
#pragma unroll
    for (int i = 0; i < 4; ++i)
#pragma unroll
        for (int j = 0; j < 2; ++j)
            acc[i][j] = (f32x16)(0.f);

    const int rswz = l32 & 7;         // row&7 for all fragment rows

    for (int kt = 0; kt < KT; ++kt) {
        const size_t tbA = (size_t)kt * AT_ELEMS;
        const size_t tbW = (size_t)kt * WT_ELEMS;
#pragma unroll
        for (int it = 0; it < 8; ++it)
            g2l16(aT + tbA + it * 2048, sAp + it * 2048);
#pragma unroll
        for (int it = 0; it < 4; ++it)
            g2l16(wT + tbW + it * 2048, sBp + it * 2048);
        __builtin_amdgcn_s_waitcnt(0);   // drain vmcnt before barrier
        __syncthreads();

#pragma unroll
        for (int s = 0; s < 4; ++s) {          // 4 k-steps of K=16
            const int cp = (s * 2 + half) ^ rswz;   // physical 16B chunk
            bf16x8 af[4], bfr[2];
#pragma unroll
            for (int mi = 0; mi < 4; ++mi)
                af[mi] = *(const bf16x8*)&sA[(wm * 128 + mi * 32 + l32) * BK + cp * 8];
#pragma unroll
            for (int ni = 0; ni < 2; ++ni)
                bfr[ni] = *(const bf16x8*)&sB[(wn * 64 + ni * 32 + l32) * BK + cp * 8];
#pragma unroll
            for (int mi = 0; mi < 4; ++mi)
#pragma unroll
                for (int ni = 0; ni < 2; ++ni)
                    acc[mi][ni] = __builtin_amdgcn_mfma_f32_32x32x16_bf16(
                        af[mi], bfr[ni], acc[mi][ni], 0, 0, 0);
        }
        __syncthreads();
    }

    // epilogue: D col = lane&31, row = (reg&3) + 8*(reg>>2) + 4*(lane>>5)
    const int colBase = bn * BN + wn * 64 + l32;
    const int rowBase = bm * BM + wm * 128 + 4 * half;
#pragma unroll
    for (int ni = 0; ni < 2; ++ni) {
        const int col = colBase + ni * 32;
        const float bv = bias[col];
#pragma unroll
        for (int mi = 0; mi < 4; ++mi) {
            const int rb = rowBase + mi * 32;
#pragma unroll
            for (int r = 0; r < 16; ++r) {
                const int row = rb + (r & 3) + 8 * (r >> 2);
                __builtin_nontemporal_store(acc[mi][ni][r] + bv,
                                            &C[(size_t)row * N_DIM + col]);
            }
        }
    }
}

// ---------------- Fallback (round-3 kernel, ws too small) ----------------
__global__ __launch_bounds__(256, 2) void linear_f32_bf16mfma_kernel(
    const float* __restrict__ A, const float* __restrict__ W,
    const float* __restrict__ bias, float* __restrict__ C)
{
    __shared__ __attribute__((aligned(16))) __bf16 sA[128 * 64];
    __shared__ __attribute__((aligned(16))) __bf16 sB[128 * 64];

    const int tid  = threadIdx.x;
    const int lane = tid & 63;
    const int wave = tid >> 6;
    const int quad = lane >> 4;
    const int l16  = lane & 15;
    const int wm   = wave >> 1;
    const int wn   = wave & 1;
    const int bn = blockIdx.x;
    const int bm = blockIdx.y;
    const int srow = tid >> 3;
    const int scol = (tid & 7) * 8;

    const float* aBase = A + (size_t)(bm * 128 + srow) * K_DIM + scol;
    const float* bBase = W + (size_t)(bn * 128 + srow) * K_DIM + scol;

    f32x4 acc[4][4];
#pragma unroll
    for (int i = 0; i < 4; ++i)
#pragma unroll
        for (int j = 0; j < 4; ++j)
            acc[i][j] = f32x4{0.f, 0.f, 0.f, 0.f};

    const int aRow = wm * 64 + l16;
    const int bRow = wn * 64 + l16;
    const int kOff = quad * 8;

    for (int k0 = 0; k0 < K_DIM; k0 += 64) {
        f32x4 ga[4][2], gb[4][2];
#pragma unroll
        for (int it = 0; it < 4; ++it) {
            const float* pa = aBase + (size_t)(it * 32) * K_DIM + k0;
            const float* pb = bBase + (size_t)(it * 32) * K_DIM + k0;
            ga[it][0] = *(const f32x4*)(pa);
            ga[it][1] = *(const f32x4*)(pa + 4);
            gb[it][0] = *(const f32x4*)(pb);
            gb[it][1] = *(const f32x4*)(pb + 4);
        }
        u32x4 wa[4], wb[4];
#pragma unroll
        for (int it = 0; it < 4; ++it) {
            wa[it] = u32x4{pack2bf(ga[it][0][0], ga[it][0][1]),
                           pack2bf(ga[it][0][2], ga[it][0][3]),
                           pack2bf(ga[it][1][0], ga[it][1][1]),
                           pack2bf(ga[it][1][2], ga[it][1][3])};
            wb[it] = u32x4{pack2bf(gb[it][0][0], gb[it][0][1]),
                           pack2bf(gb[it][0][2], gb[it][0][3]),
                           pack2bf(gb[it][1][0], gb[it][1][1]),
                           pack2bf(gb[it][1][2], gb[it][1][3])};
        }
        __syncthreads();
#pragma unroll
        for (int it = 0; it < 4; ++it) {
            *(u32x4*)&sA[tid * 8 + it * 2048] = wa[it];
            *(u32x4*)&sB[tid * 8 + it * 2048] = wb[it];
        }
        __syncthreads();
#pragma unroll
        for (int ks = 0; ks < 64; ks += 32) {
            bf16x8 af[4], bfr[4];
#pragma unroll
            for (int mi = 0; mi < 4; ++mi)
                af[mi] = *(const bf16x8*)&sA[(aRow + mi * 16) * 64 + ks + kOff];
#pragma unroll
            for (int ni = 0; ni < 4; ++ni)
                bfr[ni] = *(const bf16x8*)&sB[(bRow + ni * 16) * 64 + ks + kOff];
#pragma unroll
            for (int mi = 0; mi < 4; ++mi)
#pragma unroll
                for (int ni = 0; ni < 4; ++ni)
                    acc[mi][ni] = __builtin_amdgcn_mfma_f32_16x16x32_bf16(
                        af[mi], bfr[ni], acc[mi][ni], 0, 0, 0);
        }
    }
    const int colBase = bn * 128 + wn * 64 + l16;
    const int rowBase = bm * 128 + wm * 64 + quad * 4;
#pragma unroll
    for (int ni = 0; ni < 4; ++ni) {
        const int col = colBase + ni * 16;
        const float bv = bias[col];
#pragma unroll
        for (int mi = 0; mi < 4; ++mi) {
            const int row = rowBase + mi * 16;
#pragma unroll
            for (int r = 0; r < 4; ++r)
                C[(size_t)(row + r) * N_DIM + col] = acc[mi][ni][r] + bv;
        }
    }
}

extern "C" void kernel_launch(void* const* d_in, const int* in_sizes, int n_in,
                              void* d_out, int out_size, void* d_ws, size_t ws_size,
                              hipStream_t stream) {
    const float* x = (const float*)d_in[0];   // [8192, 4096]
    const float* w = (const float*)d_in[1];   // [4096, 4096]
    const float* b = (const float*)d_in[2];   // [4096]
    float* out = (float*)d_out;

    if (ws_size >= A_PACK_BYTES + W_PACK_BYTES) {
        u32x4* aP = (u32x4*)d_ws;
        u32x4* wP = (u32x4*)((char*)d_ws + A_PACK_BYTES);
        const long total_threads = (long)(A_CHUNKS + W_CHUNKS) / 2;
        pack_bf16_kernel<<<(int)(total_threads / 256), 256, 0, stream>>>(x, w, aP, wP);
        dim3 grid(N_DIM / BN, M_DIM / BM);    // (32, 32) = 1024 blocks
        gemm_packed_kernel<<<grid, 256, 0, stream>>>(
            (const u16*)aP, (const u16*)wP, b, out);
    } else {
        dim3 grid(N_DIM / 128, M_DIM / 128);
        linear_f32_bf16mfma_kernel<<<grid, 256, 0, stream>>>(x, w, b, out);
    }
}